// Round 1
// baseline (285.870 us; speedup 1.0000x reference)
//
#include <hip/hip_runtime.h>
#include <math.h>
#include <float.h>

#define BN 32
#define CH 3
#define HH 512
#define WW 512
#define NP 4
#define EPS 128
#define HALF 64
#define MARGIN 32

// Patches output: B*N*C*EPS*EPS floats, then coords B*N*4 floats.
#define PATCH_ELEMS (BN * NP * CH * EPS * EPS)   // 6291456

// ---------------------------------------------------------------------------
// Kernel 1: greedy masked-argmax selection. One block (1024 threads) per batch.
// ---------------------------------------------------------------------------
__global__ __launch_bounds__(1024)
void select_kernel(const float* __restrict__ umaps,
                   float* __restrict__ coords_out,   // d_out + PATCH_ELEMS, [B,N,4] float
                   int* __restrict__ coords_ws)      // [B*N*2] ints (x1,y1)
{
    const int b = blockIdx.x;
    const int tid = threadIdx.x;
    const float4* __restrict__ um4 =
        (const float4*)(umaps + (size_t)b * HH * WW);

    __shared__ int boxes[NP][4];       // expanded x1,x2,y1,y2 (with margin)
    __shared__ float swval[16];
    __shared__ int   swidx[16];

    for (int k = 0; k < NP; ++k) {
        float bv = -INFINITY;
        int   bi = 0x7fffffff;

        // Scan 512*512 = 262144 floats = 65536 float4; 1024 threads * 64 each.
        for (int t = 0; t < 64; ++t) {
            const int v4i  = tid + (t << 10);
            const float4 v = um4[v4i];
            const int base = v4i << 2;
            const int y    = base >> 9;      // row
            const int x0   = base & 511;     // col of first elem

            // y-range check per box (constant across the 4 elems)
            float vals[4] = {v.x, v.y, v.z, v.w};
            #pragma unroll
            for (int e = 0; e < 4; ++e) {
                const int xe = x0 + e;
                bool masked = false;
                for (int j = 0; j < k; ++j) {
                    masked |= (y  >= boxes[j][2]) & (y  < boxes[j][3]) &
                              (xe >= boxes[j][0]) & (xe < boxes[j][1]);
                }
                // strict > keeps first (smallest-index) max within the thread
                if (!masked && vals[e] > bv) { bv = vals[e]; bi = base + e; }
            }
        }

        // wave-level reduce (64 lanes), tie-break = smaller index
        #pragma unroll
        for (int off = 32; off > 0; off >>= 1) {
            float ov = __shfl_down(bv, off);
            int   oi = __shfl_down(bi, off);
            if (ov > bv || (ov == bv && oi < bi)) { bv = ov; bi = oi; }
        }
        const int wave = tid >> 6;
        const int lane = tid & 63;
        if (lane == 0) { swval[wave] = bv; swidx[wave] = bi; }
        __syncthreads();

        if (wave == 0) {
            bv = (lane < 16) ? swval[lane] : -INFINITY;
            bi = (lane < 16) ? swidx[lane] : 0x7fffffff;
            #pragma unroll
            for (int off = 8; off > 0; off >>= 1) {
                float ov = __shfl_down(bv, off);
                int   oi = __shfl_down(bi, off);
                if (ov > bv || (ov == bv && oi < bi)) { bv = ov; bi = oi; }
            }
            if (lane == 0) {
                const int yc = bi >> 9;
                const int xc = bi & 511;
                int x1 = max(0, xc - HALF), x2 = min(WW, xc + HALF);
                int y1 = max(0, yc - HALF), y2 = min(HH, yc + HALF);
                // fix(): force exact EPS window at borders
                if (x2 - x1 < EPS) { if (x1 == 0) x2 = EPS; else x1 = x2 - EPS; }
                if (y2 - y1 < EPS) { if (y1 == 0) y2 = EPS; else y1 = y2 - EPS; }
                boxes[k][0] = x1 - MARGIN; boxes[k][1] = x2 + MARGIN;
                boxes[k][2] = y1 - MARGIN; boxes[k][3] = y2 + MARGIN;

                const int o = (b * NP + k) * 4;
                coords_out[o + 0] = (float)x1;
                coords_out[o + 1] = (float)y1;
                coords_out[o + 2] = (float)x2;
                coords_out[o + 3] = (float)y2;
                coords_ws[(b * NP + k) * 2 + 0] = x1;
                coords_ws[(b * NP + k) * 2 + 1] = y1;
            }
        }
        __syncthreads();   // boxes[k] visible to all before next pass
    }
}

// ---------------------------------------------------------------------------
// Kernel 2: patch gather. One float per thread; out[b][n][c][py][px].
// ---------------------------------------------------------------------------
__global__ __launch_bounds__(256)
void extract_kernel(const float* __restrict__ images,
                    const int* __restrict__ coords_ws,
                    float* __restrict__ out)
{
    const int idx = blockIdx.x * 256 + threadIdx.x;   // < PATCH_ELEMS exactly
    const int px   = idx & 127;
    const int py   = (idx >> 7) & 127;
    const int rest = idx >> 14;          // b*NP*CH + n*CH + c, < 384
    const int c    = rest % CH;
    const int bn   = rest / CH;          // b*NP + n
    const int b    = bn >> 2;

    const int x1 = coords_ws[bn * 2 + 0];
    const int y1 = coords_ws[bn * 2 + 1];

    out[idx] = images[(((size_t)b * CH + c) * HH + (y1 + py)) * WW + (x1 + px)];
}

extern "C" void kernel_launch(void* const* d_in, const int* in_sizes, int n_in,
                              void* d_out, int out_size, void* d_ws, size_t ws_size,
                              hipStream_t stream) {
    const float* images = (const float*)d_in[0];
    const float* umaps  = (const float*)d_in[1];
    float* out          = (float*)d_out;
    int*   coords_ws    = (int*)d_ws;

    float* coords_out = out + PATCH_ELEMS;

    select_kernel<<<BN, 1024, 0, stream>>>(umaps, coords_out, coords_ws);

    // PATCH_ELEMS = 6291456 = 24576 * 256, exact
    extract_kernel<<<PATCH_ELEMS / 256, 256, 0, stream>>>(images, coords_ws, out);
}